// Round 7
// baseline (298.016 us; speedup 1.0000x reference)
//
#include <hip/hip_runtime.h>

// Problem constants (from reference)
#define BATCH 2
#define HH 512
#define WW 512
#define NIN 64
#define NOUT 64
#define N_NZ 131072
#define N_MASK 131072
#define NPIX (BATCH * HH * WW)   // 524288
#define PPW 64                   // points per wave in conv kernel
#define MAX_ALIVE N_MASK         // alive pixels <= number of mask points

// d_ws layout (compact path):
//   [0,256)            int counter
//   [256, +2MB)        float mask[NPIX]
//   [.., +2MB)         int   slot[NPIX]
//   [.., +32MB)        float compact[MAX_ALIVE*NOUT]
#define WS_MASK_OFF   256
#define WS_SLOT_OFF   (WS_MASK_OFF + (size_t)NPIX * 4)
#define WS_CMP_OFF    (WS_SLOT_OFF + (size_t)NPIX * 4)
#define WS_NEED       (WS_CMP_OFF + (size_t)MAX_ALIVE * NOUT * 4)

// 64-fold repetition macro: the weight slice must be 64 NAMED scalars.
// (R2..R6 evidence: `float kreg[64]` with a loop index defeats SROA —
// SROA runs before unrolling — so the array lived in SCRATCH memory and
// every alive-entry re-read 16 KB through L1. VGPR_Count=36 all along.)
#define REP64(M) \
  M(0) M(1) M(2) M(3) M(4) M(5) M(6) M(7) \
  M(8) M(9) M(10) M(11) M(12) M(13) M(14) M(15) \
  M(16) M(17) M(18) M(19) M(20) M(21) M(22) M(23) \
  M(24) M(25) M(26) M(27) M(28) M(29) M(30) M(31) \
  M(32) M(33) M(34) M(35) M(36) M(37) M(38) M(39) \
  M(40) M(41) M(42) M(43) M(44) M(45) M(46) M(47) \
  M(48) M(49) M(50) M(51) M(52) M(53) M(54) M(55) \
  M(56) M(57) M(58) M(59) M(60) M(61) M(62) M(63)

// ---------------------------------------------------------------------------
// Mask scatter:  mask[b,y,x] += mask_values[n]
// ---------------------------------------------------------------------------
__global__ void mask_scatter_kernel(const float* __restrict__ mv,
                                    const int* __restrict__ midx,
                                    float* __restrict__ mask) {
    int n = blockIdx.x * blockDim.x + threadIdx.x;
    if (n < N_MASK) {
        int b = midx[n * 3 + 0];
        int y = midx[n * 3 + 1];
        int x = midx[n * 3 + 2];
        atomicAdd(&mask[(b * HH + y) * WW + x], mv[n]);
    }
}

// ---------------------------------------------------------------------------
// Slot assignment: block-aggregated scan, ONE counter atomic per block.
// ---------------------------------------------------------------------------
__global__ __launch_bounds__(256) void build_slot2_kernel(
        const float* __restrict__ mask,
        int* __restrict__ slot,
        int* __restrict__ counter) {
    const int tid = threadIdx.x;
    const int gid = blockIdx.x * 256 + tid;     // over NPIX/4 groups
    const float4 m = reinterpret_cast<const float4*>(mask)[gid];
    const int c0 = (m.x != 0.f) + (m.y != 0.f) + (m.z != 0.f) + (m.w != 0.f);

    const int lane = tid & 63;
    const int wv = tid >> 6;
    int pre = c0;
#pragma unroll
    for (int d = 1; d < 64; d <<= 1) {
        int t = __shfl_up(pre, d);
        if (lane >= d) pre += t;
    }

    __shared__ int wsum[4];
    __shared__ int wbase[4];
    __shared__ int blockbase;
    if (lane == 63) wsum[wv] = pre;
    __syncthreads();
    if (tid == 0) {
        int s = 0;
#pragma unroll
        for (int w = 0; w < 4; ++w) { wbase[w] = s; s += wsum[w]; }
        blockbase = atomicAdd(counter, s);      // ONE atomic per block
    }
    __syncthreads();

    int s0 = blockbase + wbase[wv] + (pre - c0);  // exclusive prefix
    int4 sv;
    sv.x = (m.x != 0.f) ? s0++ : -1;
    sv.y = (m.y != 0.f) ? s0++ : -1;
    sv.z = (m.z != 0.f) ? s0++ : -1;
    sv.w = (m.w != 0.f) ? s0++ : -1;
    reinterpret_cast<int4*>(slot)[gid] = sv;
}

// ---------------------------------------------------------------------------
// Conv scatter v4: weight slice in 64 NAMED scalar VGPRs (REP64 macro).
// One wave per (tap, 64-point tile); lane = output channel.
// Probe: lane-parallel idx/slot loads + one ballot. Alive loop: values row
// via wave-uniform s_load (constant offsets), 64 named-register FMAs split
// over 4 accumulator chains, one coalesced atomicAdd into compact.
// __launch_bounds__(64,1): VGPR budget 512 — no spill pressure.
// ---------------------------------------------------------------------------
__global__ __launch_bounds__(64, 1) void conv_scatter4_kernel(
        const float* __restrict__ values,   // (N_NZ, NIN)
        const float* __restrict__ kern,     // (3,3,NIN,NOUT)
        const int* __restrict__ idx,        // (N_NZ,3) int32
        const int* __restrict__ slot,       // (NPIX,) slot id or -1
        float* __restrict__ compact) {      // (MAX_ALIVE, NOUT) zeroed
    const int bid  = blockIdx.x;
    const int tap  = bid % 9;               // 9 taps of a tile run adjacent
    const int tile = bid / 9;               // -> values rows L2-hot
    const int lane = threadIdx.x;
    const int ky = tap / 3;
    const int kx = tap % 3;

    const float* kp = kern + (size_t)tap * NIN * NOUT + lane;
#define DECLK(i) float k##i = kp[(i) * NOUT]; asm volatile("" : "+v"(k##i));
    REP64(DECLK)
#undef DECLK

    // Lane-parallel probe of 64 points' destinations.
    const int p0 = tile * PPW;
    const int p  = p0 + lane;
    const int b = idx[p * 3 + 0];
    const int y = idx[p * 3 + 1];
    const int x = idx[p * 3 + 2];
    const int sy = min(max(y + ky - 1, 0), HH - 1);
    const int sx = min(max(x + kx - 1, 0), WW - 1);
    const int pix = (b * HH + sy) * WW + sx;
    const int s = slot[pix];

    unsigned long long alive = __ballot(s >= 0);
    while (alive) {
        const int j = __ffsll((long long)alive) - 1;  // uniform (ballot)
        alive &= alive - 1;
        const int sj = __shfl(s, j);                  // slot of point j
        const float* vp = values + (size_t)(p0 + j) * NIN;  // uniform->s_load
        float acc[4] = {0.f, 0.f, 0.f, 0.f};          // 4 chains, const idx
#define FMASTEP(i) acc[(i) & 3] = fmaf(vp[i], k##i, acc[(i) & 3]);
        REP64(FMASTEP)
#undef FMASTEP
        const float a = (acc[0] + acc[1]) + (acc[2] + acc[3]);
        atomicAdd(&compact[(size_t)sj * NOUT + lane], a);
    }
}

// ---------------------------------------------------------------------------
// Streaming finalize: writes EVERY output element exactly once.
//   dead pixel  -> 0 ; alive -> (compact[slot] + m*bias) * m
// ---------------------------------------------------------------------------
__global__ void finalize2_kernel(float* __restrict__ out,
                                 const float* __restrict__ mask,
                                 const int* __restrict__ slot,
                                 const float* __restrict__ compact,
                                 const float* __restrict__ bias) {
    const int t = blockIdx.x * blockDim.x + threadIdx.x;
    const int p = t >> 4;
    const int c4 = (t & 15) * 4;
    if (p >= NPIX) return;
    float4* o = reinterpret_cast<float4*>(out + (size_t)p * NOUT + c4);
    const int s = slot[p];
    if (s < 0) {
        *o = make_float4(0.f, 0.f, 0.f, 0.f);
        return;
    }
    const float m = mask[p];
    const float4 bb = *reinterpret_cast<const float4*>(bias + c4);
    float4 v = *reinterpret_cast<const float4*>(compact + (size_t)s * NOUT + c4);
    v.x = (v.x + m * bb.x) * m;
    v.y = (v.y + m * bb.y) * m;
    v.z = (v.z + m * bb.z) * m;
    v.w = (v.w + m * bb.w) * m;
    *o = v;
}

// ======================= Fallback path (R3, proven) ========================
__global__ __launch_bounds__(64, 2) void conv_scatter_kernel(
        const float* __restrict__ values,
        const float* __restrict__ kern,
        const int* __restrict__ idx,
        const float* __restrict__ mask,
        float* __restrict__ dense) {
    const int bid  = blockIdx.x;
    const int tap  = bid % 9;
    const int tile = bid / 9;
    const int lane = threadIdx.x;
    const int ky = tap / 3;
    const int kx = tap % 3;
    float kreg[NIN];
    const float* kp = kern + (size_t)tap * NIN * NOUT + lane;
#pragma unroll
    for (int i = 0; i < NIN; ++i) kreg[i] = kp[(size_t)i * NOUT];
    const int p0 = tile * PPW;
    for (int pp = 0; pp < PPW; ++pp) {
        const int p = p0 + pp;
        const int b = idx[p * 3 + 0];
        const int y = idx[p * 3 + 1];
        const int x = idx[p * 3 + 2];
        const int sy = min(max(y + ky - 1, 0), HH - 1);
        const int sx = min(max(x + kx - 1, 0), WW - 1);
        const size_t pix = ((size_t)b * HH + sy) * WW + sx;
        if (mask[pix] != 0.0f) {
            const float* vp = values + (size_t)p * NIN;
            float acc = 0.0f;
#pragma unroll
            for (int i = 0; i < NIN; ++i) acc = fmaf(vp[i], kreg[i], acc);
            atomicAdd(&dense[pix * NOUT + lane], acc);
        }
    }
}

__global__ void finalize_kernel(float* __restrict__ out,
                                const float* __restrict__ mask,
                                const float* __restrict__ bias) {
    const int t = blockIdx.x * blockDim.x + threadIdx.x;
    const int p = t >> 4;
    const int c4 = (t & 15) * 4;
    if (p >= NPIX) return;
    const float m = mask[p];
    if (m == 0.0f) return;
    float4* o = reinterpret_cast<float4*>(out + (size_t)p * NOUT + c4);
    const float4 bb = *reinterpret_cast<const float4*>(bias + c4);
    float4 v = *o;
    v.x = (v.x + m * bb.x) * m;
    v.y = (v.y + m * bb.y) * m;
    v.z = (v.z + m * bb.z) * m;
    v.w = (v.w + m * bb.w) * m;
    *o = v;
}

extern "C" void kernel_launch(void* const* d_in, const int* in_sizes, int n_in,
                              void* d_out, int out_size, void* d_ws, size_t ws_size,
                              hipStream_t stream) {
    const float* values      = (const float*)d_in[0];
    const float* kern        = (const float*)d_in[1];
    const float* bias        = (const float*)d_in[2];
    const float* mask_values = (const float*)d_in[3];
    const int*   indices     = (const int*)d_in[4];
    const int*   mask_idx    = (const int*)d_in[5];
    float* out = (float*)d_out;

    if (ws_size >= WS_NEED) {
        // ---- compact path ----
        char* ws = (char*)d_ws;
        int*   counter = (int*)ws;
        float* mask    = (float*)(ws + WS_MASK_OFF);
        int*   slot    = (int*)(ws + WS_SLOT_OFF);
        float* compact = (float*)(ws + WS_CMP_OFF);

        hipMemsetAsync(ws, 0, WS_NEED, stream);  // counter+mask+slot+compact

        mask_scatter_kernel<<<(N_MASK + 255) / 256, 256, 0, stream>>>(
            mask_values, mask_idx, mask);
        build_slot2_kernel<<<NPIX / 4 / 256, 256, 0, stream>>>(
            mask, slot, counter);

        const int nblocks = 9 * (N_NZ / PPW);
        conv_scatter4_kernel<<<nblocks, 64, 0, stream>>>(
            values, kern, indices, slot, compact);

        const int total = NPIX * (NOUT / 4);
        finalize2_kernel<<<(total + 255) / 256, 256, 0, stream>>>(
            out, mask, slot, compact, bias);
    } else {
        // ---- fallback: R3 structure ----
        float* mask = (float*)d_ws;
        hipMemsetAsync(out, 0, (size_t)out_size * sizeof(float), stream);
        hipMemsetAsync(mask, 0, (size_t)NPIX * sizeof(float), stream);
        mask_scatter_kernel<<<(N_MASK + 255) / 256, 256, 0, stream>>>(
            mask_values, mask_idx, mask);
        const int nblocks = 9 * (N_NZ / PPW);
        conv_scatter_kernel<<<nblocks, 64, 0, stream>>>(
            values, kern, indices, mask, out);
        const int total = NPIX * (NOUT / 4);
        finalize_kernel<<<(total + 255) / 256, 256, 0, stream>>>(out, mask, bias);
    }
}

// Round 8
// 266.759 us; speedup vs baseline: 1.1172x; 1.1172x over previous
//
#include <hip/hip_runtime.h>

// Problem constants (from reference)
#define BATCH 2
#define HH 512
#define WW 512
#define NIN 64
#define NOUT 64
#define N_NZ 131072
#define N_MASK 131072
#define NPIX (BATCH * HH * WW)   // 524288
#define MAX_ALIVE N_MASK

// d_ws layout:
//   [0,256)            int counter
//   [256, +2MB)        float mask[NPIX]
//   [.., +2MB)         int   slot[NPIX]
//   [.., +32MB)        float compact[MAX_ALIVE*NOUT]
//   [.., +72KB)        bf16  kt[9][NOUT][NIN]  (transposed weights)
#define WS_MASK_OFF   256
#define WS_SLOT_OFF   (WS_MASK_OFF + (size_t)NPIX * 4)
#define WS_CMP_OFF    (WS_SLOT_OFF + (size_t)NPIX * 4)
#define WS_KT_OFF     (WS_CMP_OFF + (size_t)MAX_ALIVE * NOUT * 4)
#define WS_NEED2      (WS_KT_OFF + (size_t)9 * NIN * NOUT * 2)
#define WS_NEED_R5    WS_KT_OFF

typedef short s8v  __attribute__((ext_vector_type(8)));   // 8 bf16
typedef float f4v  __attribute__((ext_vector_type(4)));   // 4 fp32 acc

__device__ __forceinline__ short f2bf(float f) {
    unsigned u = __builtin_bit_cast(unsigned, f);
    unsigned r = u + 0x7FFFu + ((u >> 16) & 1u);   // RNE
    return (short)(r >> 16);
}

// ---------------------------------------------------------------------------
// Mask scatter:  mask[b,y,x] += mask_values[n]
// ---------------------------------------------------------------------------
__global__ void mask_scatter_kernel(const float* __restrict__ mv,
                                    const int* __restrict__ midx,
                                    float* __restrict__ mask) {
    int n = blockIdx.x * blockDim.x + threadIdx.x;
    if (n < N_MASK) {
        int b = midx[n * 3 + 0];
        int y = midx[n * 3 + 1];
        int x = midx[n * 3 + 2];
        atomicAdd(&mask[(b * HH + y) * WW + x], mv[n]);
    }
}

// ---------------------------------------------------------------------------
// Slot assignment: block-aggregated scan, ONE counter atomic per block.
// ---------------------------------------------------------------------------
__global__ __launch_bounds__(256) void build_slot2_kernel(
        const float* __restrict__ mask,
        int* __restrict__ slot,
        int* __restrict__ counter) {
    const int tid = threadIdx.x;
    const int gid = blockIdx.x * 256 + tid;     // over NPIX/4 groups
    const float4 m = reinterpret_cast<const float4*>(mask)[gid];
    const int c0 = (m.x != 0.f) + (m.y != 0.f) + (m.z != 0.f) + (m.w != 0.f);

    const int lane = tid & 63;
    const int wv = tid >> 6;
    int pre = c0;
#pragma unroll
    for (int d = 1; d < 64; d <<= 1) {
        int t = __shfl_up(pre, d);
        if (lane >= d) pre += t;
    }

    __shared__ int wsum[4];
    __shared__ int wbase[4];
    __shared__ int blockbase;
    if (lane == 63) wsum[wv] = pre;
    __syncthreads();
    if (tid == 0) {
        int s = 0;
#pragma unroll
        for (int w = 0; w < 4; ++w) { wbase[w] = s; s += wsum[w]; }
        blockbase = atomicAdd(counter, s);
    }
    __syncthreads();

    int s0 = blockbase + wbase[wv] + (pre - c0);
    int4 sv;
    sv.x = (m.x != 0.f) ? s0++ : -1;
    sv.y = (m.y != 0.f) ? s0++ : -1;
    sv.z = (m.z != 0.f) ? s0++ : -1;
    sv.w = (m.w != 0.f) ? s0++ : -1;
    reinterpret_cast<int4*>(slot)[gid] = sv;
}

// ---------------------------------------------------------------------------
// Weight transpose + bf16 convert:  kt[tap][c][i] = bf16(kern[tap][i][c])
// 36864 elems, trivial cost.
// ---------------------------------------------------------------------------
__global__ void convert_kt_kernel(const float* __restrict__ kern,
                                  short* __restrict__ kt) {
    int t = blockIdx.x * 256 + threadIdx.x;
    if (t < 9 * NIN * NOUT) {
        int tap = t >> 12;
        int rem = t & 4095;
        int c = rem >> 6;          // out channel
        int i = rem & 63;          // in channel
        kt[tap * 4096 + c * 64 + i] = f2bf(kern[tap * 4096 + i * 64 + c]);
    }
}

// ---------------------------------------------------------------------------
// Conv via MFMA. Block = 256 thr = 4 waves; each wave owns 16 points.
// Per wave: A-frags (16 points x 64 in-ch, bf16, converted on the fly) are
// loaded ONCE; loop over 9 taps: probe destinations (16 lanes, ballot skip),
// then 16x64 = 4 n-tiles x 2 k-steps of mfma_f32_16x16x32_bf16 against the
// transposed weight rows (8 KB/tap shared via L1 across 4 waves x 4 tiles),
// then per-row predicated coalesced atomicAdd of alive rows into compact.
// Weight movement per point-tap: ~512 B vs 16 KB in R2..R7 (the L1-port
// bound that pinned conv at ~91 us). MFMA frags are ext-vector SSA — no
// scratch-array / register-allocator fight.
// Layouts (guide §3, m89/m118-verified): A[m=lane&15][k=(lane>>4)*8+j],
// B[k=(lane>>4)*8+j][n=lane&15], C/D col=lane&15 row=(lane>>4)*4+reg.
// ---------------------------------------------------------------------------
__global__ __launch_bounds__(256) void conv_mfma_kernel(
        const float* __restrict__ values,   // (N_NZ, NIN) fp32
        const short* __restrict__ kt,       // (9, NOUT, NIN) bf16 transposed
        const int* __restrict__ idx,        // (N_NZ, 3) int32
        const int* __restrict__ slot,       // (NPIX,) slot or -1
        float* __restrict__ compact) {      // (MAX_ALIVE, NOUT) zeroed
    const int wid  = threadIdx.x >> 6;      // wave 0..3
    const int lane = threadIdx.x & 63;
    const int q    = lane >> 4;             // quad 0..3
    const int col  = lane & 15;
    const int p0   = blockIdx.x * 64 + wid * 16;   // this wave's 16 points

    // ---- A fragments: rows = 16 points, k = 64 in-ch, fp32 -> bf16 ----
    const float* vrow = values + (size_t)(p0 + col) * NIN + q * 8;
    s8v a0, a1;
#pragma unroll
    for (int j = 0; j < 8; ++j) {
        a0[j] = f2bf(vrow[j]);
        a1[j] = f2bf(vrow[32 + j]);
    }

    // ---- probe coords for this lane's point (lane&15) ----
    const int pme = p0 + col;
    const int b = idx[pme * 3 + 0];
    const int y = idx[pme * 3 + 1];
    const int x = idx[pme * 3 + 2];

    for (int tap = 0; tap < 9; ++tap) {
        const int ky = tap / 3;
        const int kx = tap % 3;
        const int sy = min(max(y + ky - 1, 0), HH - 1);
        const int sx = min(max(x + kx - 1, 0), WW - 1);
        const int s = slot[(b * HH + sy) * WW + sx];

        if (__ballot(s >= 0) == 0ULL) continue;   // whole 16-group dead

        const short* ktt = kt + tap * 4096;
        // B-frag row base for this lane: out-channel (16t+col), k-run q*8
        const short* kb = ktt + col * 64 + q * 8;

        f4v c0 = {0.f, 0.f, 0.f, 0.f};
        f4v c1 = {0.f, 0.f, 0.f, 0.f};
        f4v c2 = {0.f, 0.f, 0.f, 0.f};
        f4v c3 = {0.f, 0.f, 0.f, 0.f};

        s8v b0a = *(const s8v*)(kb + 0 * 16 * 64);
        s8v b0b = *(const s8v*)(kb + 0 * 16 * 64 + 32);
        c0 = __builtin_amdgcn_mfma_f32_16x16x32_bf16(a0, b0a, c0, 0, 0, 0);
        c0 = __builtin_amdgcn_mfma_f32_16x16x32_bf16(a1, b0b, c0, 0, 0, 0);
        s8v b1a = *(const s8v*)(kb + 1 * 16 * 64);
        s8v b1b = *(const s8v*)(kb + 1 * 16 * 64 + 32);
        c1 = __builtin_amdgcn_mfma_f32_16x16x32_bf16(a0, b1a, c1, 0, 0, 0);
        c1 = __builtin_amdgcn_mfma_f32_16x16x32_bf16(a1, b1b, c1, 0, 0, 0);
        s8v b2a = *(const s8v*)(kb + 2 * 16 * 64);
        s8v b2b = *(const s8v*)(kb + 2 * 16 * 64 + 32);
        c2 = __builtin_amdgcn_mfma_f32_16x16x32_bf16(a0, b2a, c2, 0, 0, 0);
        c2 = __builtin_amdgcn_mfma_f32_16x16x32_bf16(a1, b2b, c2, 0, 0, 0);
        s8v b3a = *(const s8v*)(kb + 3 * 16 * 64);
        s8v b3b = *(const s8v*)(kb + 3 * 16 * 64 + 32);
        c3 = __builtin_amdgcn_mfma_f32_16x16x32_bf16(a0, b3a, c3, 0, 0, 0);
        c3 = __builtin_amdgcn_mfma_f32_16x16x32_bf16(a1, b3b, c3, 0, 0, 0);

        // ---- scatter alive rows: D row = q*4+r, channel = tile*16+col ----
#pragma unroll
        for (int r = 0; r < 4; ++r) {
            const int mr = q * 4 + r;           // point row 0..15
            const int sr = __shfl(s, mr);       // its slot (lane mr holds it)
            if (sr >= 0) {
                float* dst = compact + (size_t)sr * NOUT + col;
                atomicAdd(dst + 0,  c0[r]);
                atomicAdd(dst + 16, c1[r]);
                atomicAdd(dst + 32, c2[r]);
                atomicAdd(dst + 48, c3[r]);
            }
        }
    }
}

// ---------------------------------------------------------------------------
// Streaming finalize: writes EVERY output element exactly once.
// ---------------------------------------------------------------------------
__global__ void finalize2_kernel(float* __restrict__ out,
                                 const float* __restrict__ mask,
                                 const int* __restrict__ slot,
                                 const float* __restrict__ compact,
                                 const float* __restrict__ bias) {
    const int t = blockIdx.x * blockDim.x + threadIdx.x;
    const int p = t >> 4;
    const int c4 = (t & 15) * 4;
    if (p >= NPIX) return;
    float4* o = reinterpret_cast<float4*>(out + (size_t)p * NOUT + c4);
    const int s = slot[p];
    if (s < 0) {
        *o = make_float4(0.f, 0.f, 0.f, 0.f);
        return;
    }
    const float m = mask[p];
    const float4 bb = *reinterpret_cast<const float4*>(bias + c4);
    float4 v = *reinterpret_cast<const float4*>(compact + (size_t)s * NOUT + c4);
    v.x = (v.x + m * bb.x) * m;
    v.y = (v.y + m * bb.y) * m;
    v.z = (v.z + m * bb.z) * m;
    v.w = (v.w + m * bb.w) * m;
    *o = v;
}

// ============== Fallback: R5 compact-path VALU conv (proven) ===============
__global__ __launch_bounds__(64, 2) void conv_scatter3_kernel(
        const float* __restrict__ values,
        const float* __restrict__ kern,
        const int* __restrict__ idx,
        const int* __restrict__ slot,
        float* __restrict__ compact) {
    const int bid  = blockIdx.x;
    const int tap  = bid % 9;
    const int tile = bid / 9;
    const int lane = threadIdx.x;
    const int ky = tap / 3;
    const int kx = tap % 3;
    float kreg[NIN];
    const float* kp = kern + (size_t)tap * NIN * NOUT + lane;
#pragma unroll
    for (int i = 0; i < NIN; ++i) kreg[i] = kp[(size_t)i * NOUT];
    const int p0 = tile * 64;
    const int p  = p0 + lane;
    const int b = idx[p * 3 + 0];
    const int y = idx[p * 3 + 1];
    const int x = idx[p * 3 + 2];
    const int sy = min(max(y + ky - 1, 0), HH - 1);
    const int sx = min(max(x + kx - 1, 0), WW - 1);
    const int pix = (b * HH + sy) * WW + sx;
    const int s = slot[pix];
    unsigned long long alive = __ballot(s >= 0);
    while (alive) {
        const int j = __ffsll((long long)alive) - 1;
        alive &= alive - 1;
        const int sj = __shfl(s, j);
        const float* vp = values + (size_t)(p0 + j) * NIN;
        float acc = 0.0f;
#pragma unroll
        for (int i = 0; i < NIN; ++i) acc = fmaf(vp[i], kreg[i], acc);
        atomicAdd(&compact[(size_t)sj * NOUT + lane], acc);
    }
}

extern "C" void kernel_launch(void* const* d_in, const int* in_sizes, int n_in,
                              void* d_out, int out_size, void* d_ws, size_t ws_size,
                              hipStream_t stream) {
    const float* values      = (const float*)d_in[0];
    const float* kern        = (const float*)d_in[1];
    const float* bias        = (const float*)d_in[2];
    const float* mask_values = (const float*)d_in[3];
    const int*   indices     = (const int*)d_in[4];
    const int*   mask_idx    = (const int*)d_in[5];
    float* out = (float*)d_out;

    char* ws = (char*)d_ws;
    int*   counter = (int*)ws;
    float* mask    = (float*)(ws + WS_MASK_OFF);
    int*   slot    = (int*)(ws + WS_SLOT_OFF);
    float* compact = (float*)(ws + WS_CMP_OFF);
    short* kt      = (short*)(ws + WS_KT_OFF);

    const bool mfma_path = (ws_size >= WS_NEED2);
    const size_t zero_span = mfma_path ? WS_NEED2 : WS_NEED_R5;

    hipMemsetAsync(ws, 0, zero_span, stream);

    mask_scatter_kernel<<<(N_MASK + 255) / 256, 256, 0, stream>>>(
        mask_values, mask_idx, mask);
    build_slot2_kernel<<<NPIX / 4 / 256, 256, 0, stream>>>(
        mask, slot, counter);

    if (mfma_path) {
        convert_kt_kernel<<<(9 * NIN * NOUT + 255) / 256, 256, 0, stream>>>(
            kern, kt);
        conv_mfma_kernel<<<N_NZ / 64, 256, 0, stream>>>(
            values, kt, indices, slot, compact);
    } else {
        conv_scatter3_kernel<<<9 * (N_NZ / 64), 64, 0, stream>>>(
            values, kern, indices, slot, compact);
    }

    const int total = NPIX * (NOUT / 4);
    finalize2_kernel<<<(total + 255) / 256, 256, 0, stream>>>(
        out, mask, slot, compact, bias);
}